// Round 1
// baseline (19.278 us; speedup 1.0000x reference)
//
#include <hip/hip_runtime.h>

// out[b, 3p+r, 3q+c] = 0                          if p == q
//                    = ±H[b, 3p+r, 3q+c]          otherwise,
// sign = -1 iff (u_s[b, max(p,q)] < 0) && ((r==2) XOR (c==2))
//
// One block per (row R, batch b); 384 threads, one float4 each -> full
// 1536-column row. p, r are block-uniform; per-lane work is q=C/3 (magic
// mul) + one L1-cached u_s load per component.
__global__ void jflip_kernel(const float* __restrict__ H,
                             const float* __restrict__ u_s,
                             float* __restrict__ out,
                             int N, int D) {
    const int b = blockIdx.y;
    const int R = blockIdx.x;
    const int p = R / 3;          // row block index (block-uniform)
    const int r = R - 3 * p;      // row within 3x3 block
    const bool r2 = (r == 2);

    const long long rowOff = (long long)b * D * D + (long long)R * D;
    const int C0 = threadIdx.x * 4;
    if (C0 >= D) return;

    const float* usb = u_s + (long long)b * N;

    float4 h = *reinterpret_cast<const float4*>(H + rowOff + C0);
    float hv[4] = {h.x, h.y, h.z, h.w};
    float ov[4];

#pragma unroll
    for (int k = 0; k < 4; ++k) {
        const int C = C0 + k;
        const int q = C / 3;      // constant divisor -> v_mul_hi magic
        const int c = C - 3 * q;
        if (q == p) {
            ov[k] = 0.0f;         // diagonal 3x3 block stays zero
        } else {
            const int mx = (p > q) ? p : q;
            const bool ind = usb[mx] < 0.0f;
            const bool flip = ind && (r2 != (c == 2));
            ov[k] = flip ? -hv[k] : hv[k];
        }
    }

    float4 o = make_float4(ov[0], ov[1], ov[2], ov[3]);
    *reinterpret_cast<float4*>(out + rowOff + C0) = o;
}

extern "C" void kernel_launch(void* const* d_in, const int* in_sizes, int n_in,
                              void* d_out, int out_size, void* d_ws, size_t ws_size,
                              hipStream_t stream) {
    const float* H   = (const float*)d_in[0];
    const float* u_s = (const float*)d_in[1];
    float* out = (float*)d_out;

    // Derive shapes: in_sizes[0] = B*(3N)^2 = 9*B*N^2, in_sizes[1] = B*N
    const long long nH  = (long long)in_sizes[0];
    const long long nUs = (long long)in_sizes[1];
    const int N = (int)(nH / (9LL * nUs));   // = 512
    const int B = (int)(nUs / N);            // = 4
    const int D = 3 * N;                     // = 1536

    dim3 grid((unsigned)D, (unsigned)B);     // one block per output row
    dim3 block((unsigned)(D / 4));           // 384 threads, float4 each

    jflip_kernel<<<grid, block, 0, stream>>>(H, u_s, out, N, D);
}